// Round 2
// baseline (582.722 us; speedup 1.0000x reference)
//
#include <hip/hip_runtime.h>
#include <cstdint>
#include <cstddef>

// ---------- types ----------
typedef __attribute__((ext_vector_type(8))) __bf16 bf8_t;   // MFMA A/B frag (4 VGPR)
typedef __attribute__((ext_vector_type(8))) short s8_t;     // 16B raw copy
typedef __attribute__((ext_vector_type(4))) short s4_t;     // 8B raw
typedef __attribute__((ext_vector_type(4))) float f4_t;     // MFMA C/D frag

__device__ __forceinline__ float bf2f(unsigned short h) {
  union { unsigned u; float f; } v; v.u = (unsigned)h << 16; return v.f;
}
__device__ __forceinline__ unsigned short f2bf(float f) {
  union { float f; unsigned u; } v; v.f = f;
  return (unsigned short)((v.u + 0x7FFFu + ((v.u >> 16) & 1u)) >> 16);
}

#define GL16(gp, lp) __builtin_amdgcn_global_load_lds( \
    (__attribute__((address_space(1))) void*)(gp),     \
    (__attribute__((address_space(3))) void*)(lp), 16, 0, 0)

// ---------- fp32 -> bf16 conversion ----------
__global__ void k_f32_to_bf16(const float* __restrict__ in,
                              unsigned short* __restrict__ out, int n4) {
  int i = blockIdx.x * blockDim.x + threadIdx.x;
  if (i >= n4) return;
  float4 v = reinterpret_cast<const float4*>(in)[i];
  s4_t o;
  o.x = (short)f2bf(v.x); o.y = (short)f2bf(v.y);
  o.z = (short)f2bf(v.z); o.w = (short)f2bf(v.w);
  reinterpret_cast<s4_t*>(out)[i] = o;
}

// ---------- RoPE cos/sin table (T=1024, 64 freqs) ----------
__global__ void k_rope_table(float* __restrict__ cosT, float* __restrict__ sinT) {
  int t = blockIdx.x, d = threadIdx.x;            // 1024 x 64
  float inv = exp2f(-(float)d * (13.287712379549449f / 64.0f)); // 10000^(-d/64)
  float ang = (float)t * inv;
  cosT[t * 64 + d] = cosf(ang);
  sinT[t * 64 + d] = sinf(ang);
}

// ---------- LoRA u = X_bf16 @ dA^T   (u: [B][4][16][1024] f32) ----------
__global__ __launch_bounds__(256) void k_lora_u(
    const unsigned short* __restrict__ X,   // (B,T,2048) bf16
    const float* __restrict__ dl,           // (B,128,2048) f32
    float* __restrict__ u, int pstart, int pcount) {
  __shared__ unsigned short xs[8 * 2048];   // 32 KB, 8 t-rows
  int b = blockIdx.y;
  int t0 = blockIdx.x * 8;
  const unsigned short* Xrow = X + ((size_t)b * 1024 + t0) * 2048;
  for (int idx = threadIdx.x * 8; idx < 16384; idx += 2048)
    *(s8_t*)(xs + idx) = *(const s8_t*)(Xrow + idx);
  __syncthreads();
  int w = threadIdx.x >> 6, lane = threadIdx.x & 63;
  for (int pr = w; pr < pcount * 16; pr += 4) {
    int p = pstart + (pr >> 4);
    int r = pr & 15;
    const float* dA = dl + ((size_t)b * 128 + p * 32 + r) * 2048;
    float da[32];
#pragma unroll
    for (int j = 0; j < 32; ++j) da[j] = dA[j * 64 + lane];
    for (int tl = 0; tl < 8; ++tl) {
      float acc = 0.0f;
#pragma unroll
      for (int j = 0; j < 32; ++j)
        acc += bf2f(xs[tl * 2048 + j * 64 + lane]) * da[j];
#pragma unroll
      for (int off = 32; off > 0; off >>= 1) acc += __shfl_xor(acc, off);
      if (lane == 0)
        u[(((size_t)b * 4 + p) * 16 + r) * 1024 + t0 + tl] = acc;
    }
  }
}

// ---------- 128x128 bf16 GEMM (A:MxK, Bw:NxK both K-major) + LoRA epilogue ----------
// mode 0: out (B,H,T,D) bf16   mode 1: out (B,H,D,T) bf16   mode 2: out (B,T,C) f32
#define BM 128
#define BN 128
#define BKK 64
__global__ __launch_bounds__(256, 2) void k_gemm(
    const unsigned short* __restrict__ A,
    const unsigned short* __restrict__ Bw,
    const float* __restrict__ u,
    const float* __restrict__ dl,
    void* __restrict__ outv, int p, int mode) {
  constexpr int K = 2048;
  __shared__ unsigned short As[BM * BKK];   // 16 KB
  __shared__ unsigned short Bs[BN * BKK];   // 16 KB
  const int t = threadIdx.x;
  const int m0 = blockIdx.y * BM;
  const int n0 = blockIdx.x * BN;
  const int lane = t & 63;
  const int w = t >> 6;
  const int wr = (w >> 1) * 64, wc = (w & 1) * 64;
  const int lr = lane & 15;
  const int lg = lane >> 4;
  const int lk = lg * 8;
  const int srow = t >> 3;          // 0..31
  const int scol = (t & 7) * 8;     // 0..56 (elems)
  f4_t acc[4][4] = {};

  for (int k0 = 0; k0 < K; k0 += BKK) {
#pragma unroll
    for (int j = 0; j < 4; ++j) {
      int row = j * 32 + srow;
      GL16(A  + (size_t)(m0 + row) * K + k0 + scol, As + row * BKK + scol);
      GL16(Bw + (size_t)(n0 + row) * K + k0 + scol, Bs + row * BKK + scol);
    }
    __syncthreads();
#pragma unroll
    for (int kk = 0; kk < BKK; kk += 32) {
      bf8_t af[4], bfr[4];
#pragma unroll
      for (int m = 0; m < 4; ++m)
        af[m] = *(const bf8_t*)&As[(wr + m * 16 + lr) * BKK + kk + lk];
#pragma unroll
      for (int n = 0; n < 4; ++n)
        bfr[n] = *(const bf8_t*)&Bs[(wc + n * 16 + lr) * BKK + kk + lk];
#pragma unroll
      for (int m = 0; m < 4; ++m)
#pragma unroll
        for (int n = 0; n < 4; ++n)
          acc[m][n] = __builtin_amdgcn_mfma_f32_16x16x32_bf16(af[m], bfr[n], acc[m][n], 0, 0, 0);
    }
    __syncthreads();
  }

  // LoRA rank-16 as one zero-padded K=32 MFMA step
  const int b = m0 >> 10;
  const int t0r = m0 & 1023;
  for (int idx = t; idx < 128 * 32; idx += 256) {
    int rr = idx >> 5, r = idx & 31;
    float val = (r < 16) ? u[(((size_t)b * 4 + p) * 16 + r) * 1024 + t0r + rr] : 0.0f;
    As[rr * 32 + r] = f2bf(val);
  }
  for (int idx = t; idx < 128 * 32; idx += 256) {
    int cc = idx >> 5, r = idx & 31;
    float val = (r < 16) ? dl[((size_t)b * 128 + p * 32 + 16 + r) * 2048 + n0 + cc] : 0.0f;
    Bs[cc * 32 + r] = f2bf(val);
  }
  __syncthreads();
  {
    bf8_t af[4], bfr[4];
#pragma unroll
    for (int m = 0; m < 4; ++m)
      af[m] = *(const bf8_t*)&As[(wr + m * 16 + lr) * 32 + lk];
#pragma unroll
    for (int n = 0; n < 4; ++n)
      bfr[n] = *(const bf8_t*)&Bs[(wc + n * 16 + lr) * 32 + lk];
#pragma unroll
    for (int m = 0; m < 4; ++m)
#pragma unroll
      for (int n = 0; n < 4; ++n)
        acc[m][n] = __builtin_amdgcn_mfma_f32_16x16x32_bf16(af[m], bfr[n], acc[m][n], 0, 0, 0);
  }

  // write (C/D map: col = lane&15, row = (lane>>4)*4 + reg)
  unsigned short* out16 = (unsigned short*)outv;
  float* out32 = (float*)outv;
#pragma unroll
  for (int m = 0; m < 4; ++m) {
    int ri = wr + m * 16 + lg * 4;
#pragma unroll
    for (int j = 0; j < 4; ++j) {
      int grow = m0 + ri + j;
      int gb = grow >> 10, gt = grow & 1023;
#pragma unroll
      for (int n = 0; n < 4; ++n) {
        int gcol = n0 + wc + n * 16 + lr;
        float fv = acc[m][n][j];
        if (mode == 0) {
          size_t dst = (((size_t)gb * 16 + (gcol >> 7)) * 1024 + gt) * 128 + (gcol & 127);
          out16[dst] = f2bf(fv);
        } else if (mode == 1) {
          size_t dst = (((size_t)gb * 16 + (gcol >> 7)) * 128 + (gcol & 127)) * 1024 + gt;
          out16[dst] = f2bf(fv);
        } else {
          out32[(size_t)grow * 2048 + gcol] = fv;   // final output is FLOAT32
        }
      }
    }
  }
}

// ---------- in-place RoPE on (B,H,T,128) bf16 ----------
__global__ void k_rope(unsigned short* __restrict__ X,
                       const float* __restrict__ cosT, const float* __restrict__ sinT) {
  int idx = blockIdx.x * 256 + threadIdx.x;     // B*H*T*8 = 524288
  int d0 = (idx & 7) * 8;
  int tt = (idx >> 3) & 1023;
  size_t base = (size_t)(idx >> 3) * 128 + d0;  // (bh*1024+t)*128 + d0
  s8_t a = *(s8_t*)&X[base];
  s8_t bb = *(s8_t*)&X[base + 64];
  float4 c0 = *(const float4*)&cosT[tt * 64 + d0];
  float4 c1 = *(const float4*)&cosT[tt * 64 + d0 + 4];
  float4 sv0 = *(const float4*)&sinT[tt * 64 + d0];
  float4 sv1 = *(const float4*)&sinT[tt * 64 + d0 + 4];
  float cv[8] = {c0.x, c0.y, c0.z, c0.w, c1.x, c1.y, c1.z, c1.w};
  float sw[8] = {sv0.x, sv0.y, sv0.z, sv0.w, sv1.x, sv1.y, sv1.z, sv1.w};
  s8_t ra, rb;
#pragma unroll
  for (int j = 0; j < 8; ++j) {
    float av = bf2f((unsigned short)a[j]);
    float bv = bf2f((unsigned short)bb[j]);
    ra[j] = (short)f2bf(av * cv[j] - bv * sw[j]);
    rb[j] = (short)f2bf(bv * cv[j] + av * sw[j]);
  }
  *(s8_t*)&X[base] = ra;
  *(s8_t*)&X[base + 64] = rb;
}

// ---------- fused attention (non-causal, online softmax) ----------
// Q,K: (B,H,T,128) bf16  Vt: (B,H,128,T) bf16  Y: (B,T,2048) bf16
__global__ __launch_bounds__(256) void k_attn(
    const unsigned short* __restrict__ Qg,
    const unsigned short* __restrict__ Kg,
    const unsigned short* __restrict__ Vt,
    unsigned short* __restrict__ Y) {
  const float scale = 0.08838834764831845f;  // 1/sqrt(128)
  const float L2E = 1.4426950408889634f;
  int bh = blockIdx.x >> 4;
  int b = bh >> 4, h = bh & 15;
  int w = threadIdx.x >> 6, lane = threadIdx.x & 63;
  int q0 = (blockIdx.x & 15) * 64 + w * 16;
  int lr = lane & 15, lg = lane >> 4;
  const unsigned short* Q  = Qg + (size_t)bh * 1024 * 128;
  const unsigned short* Kp = Kg + (size_t)bh * 1024 * 128;
  const unsigned short* Vp = Vt + (size_t)bh * 1024 * 128;
  __shared__ __align__(16) unsigned short P_lds[4][16][40];  // padded rows
  unsigned short (*Pw)[40] = P_lds[w];

  bf8_t qf[4];
#pragma unroll
  for (int kk = 0; kk < 4; ++kk)
    qf[kk] = *(const bf8_t*)&Q[(size_t)(q0 + lr) * 128 + kk * 32 + lg * 8];

  f4_t o[8] = {};
  float m_run = -1e30f, l_run = 0.0f;

  for (int s0 = 0; s0 < 1024; s0 += 32) {
    f4_t sf[2];
#pragma unroll
    for (int ss = 0; ss < 2; ++ss) {
      f4_t c = 0.0f;
#pragma unroll
      for (int kk = 0; kk < 4; ++kk) {
        bf8_t kf = *(const bf8_t*)&Kp[(size_t)(s0 + ss * 16 + lr) * 128 + kk * 32 + lg * 8];
        c = __builtin_amdgcn_mfma_f32_16x16x32_bf16(kf, qf[kk], c, 0, 0, 0);
      }
      sf[ss] = c;  // lane holds S[q=q0+lr][s0+ss*16+lg*4+reg]
    }
    float vmax = -1e30f;
#pragma unroll
    for (int ss = 0; ss < 2; ++ss)
#pragma unroll
      for (int j = 0; j < 4; ++j) vmax = fmaxf(vmax, sf[ss][j]);
    vmax = fmaxf(vmax, __shfl_xor(vmax, 16));
    vmax = fmaxf(vmax, __shfl_xor(vmax, 32));
    float m_new = fmaxf(m_run, vmax * scale);
    float ratio = exp2f((m_run - m_new) * L2E);
    float ps[2][4];
    float lsum = 0.0f;
#pragma unroll
    for (int ss = 0; ss < 2; ++ss)
#pragma unroll
      for (int j = 0; j < 4; ++j) {
        float pv = exp2f((sf[ss][j] * scale - m_new) * L2E);
        ps[ss][j] = pv; lsum += pv;
      }
    lsum += __shfl_xor(lsum, 16);
    lsum += __shfl_xor(lsum, 32);
    l_run = l_run * ratio + lsum;
    m_run = m_new;
    float rq[4];
#pragma unroll
    for (int j = 0; j < 4; ++j) rq[j] = __shfl(ratio, lg * 4 + j);
#pragma unroll
    for (int n = 0; n < 8; ++n)
#pragma unroll
      for (int j = 0; j < 4; ++j) o[n][j] *= rq[j];
    // P -> LDS (A-frag layout: row=q, k=s_local)
#pragma unroll
    for (int ss = 0; ss < 2; ++ss) {
      s4_t pk;
      pk.x = (short)f2bf(ps[ss][0]); pk.y = (short)f2bf(ps[ss][1]);
      pk.z = (short)f2bf(ps[ss][2]); pk.w = (short)f2bf(ps[ss][3]);
      *(s4_t*)&Pw[lr][ss * 16 + lg * 4] = pk;
    }
    bf8_t pa = *(const bf8_t*)&Pw[lr][lg * 8];
#pragma unroll
    for (int n = 0; n < 8; ++n) {
      bf8_t vf = *(const bf8_t*)&Vp[(size_t)(n * 16 + lr) * 1024 + s0 + lg * 8];
      o[n] = __builtin_amdgcn_mfma_f32_16x16x32_bf16(pa, vf, o[n], 0, 0, 0);
    }
  }

  float linv[4];
#pragma unroll
  for (int j = 0; j < 4; ++j) linv[j] = 1.0f / __shfl(l_run, lg * 4 + j);
#pragma unroll
  for (int n = 0; n < 8; ++n)
#pragma unroll
    for (int j = 0; j < 4; ++j) {
      int qg = q0 + lg * 4 + j;
      Y[((size_t)b * 1024 + qg) * 2048 + h * 128 + n * 16 + lr] =
          f2bf(o[n][j] * linv[j]);
    }
}

// ---------- launch ----------
extern "C" void kernel_launch(void* const* d_in, const int* in_sizes, int n_in,
                              void* d_out, int out_size, void* d_ws, size_t ws_size,
                              hipStream_t stream) {
  const float* x  = (const float*)d_in[0];
  const float* dl = (const float*)d_in[1];
  const float* W[4] = {(const float*)d_in[2], (const float*)d_in[3],
                       (const float*)d_in[4], (const float*)d_in[5]};
  char* ws = (char*)d_ws;
  size_t off = 0;
  auto take = [&](size_t bytes) {
    void* p = ws + off; off += (bytes + 255) & ~(size_t)255; return p;
  };
  unsigned short* xb = (unsigned short*)take(8388608ull * 2);
  unsigned short* Wb[4];
  for (int i = 0; i < 4; ++i) Wb[i] = (unsigned short*)take(4194304ull * 2);
  unsigned short* qb = (unsigned short*)take(8388608ull * 2);
  unsigned short* kb = (unsigned short*)take(8388608ull * 2);
  unsigned short* vT = (unsigned short*)take(8388608ull * 2);
  unsigned short* y  = (unsigned short*)take(8388608ull * 2);
  float* u    = (float*)take(4ull * 4 * 16 * 1024 * 4);
  float* cosT = (float*)take(1024ull * 64 * 4);
  float* sinT = (float*)take(1024ull * 64 * 4);
  if (off > ws_size) return;  // workspace too small -> visible validation failure

  k_f32_to_bf16<<<8192, 256, 0, stream>>>(x, xb, 2097152);
  for (int i = 0; i < 4; ++i)
    k_f32_to_bf16<<<4096, 256, 0, stream>>>(W[i], Wb[i], 1048576);
  k_rope_table<<<1024, 64, 0, stream>>>(cosT, sinT);
  k_lora_u<<<dim3(128, 4), 256, 0, stream>>>(xb, dl, u, 0, 3);
  dim3 gg(16, 32);
  k_gemm<<<gg, 256, 0, stream>>>(xb, Wb[0], u, dl, qb, 0, 0);
  k_gemm<<<gg, 256, 0, stream>>>(xb, Wb[1], u, dl, kb, 1, 0);
  k_gemm<<<gg, 256, 0, stream>>>(xb, Wb[2], u, dl, vT, 2, 1);
  k_rope<<<2048, 256, 0, stream>>>(qb, cosT, sinT);
  k_rope<<<2048, 256, 0, stream>>>(kb, cosT, sinT);
  k_attn<<<1024, 256, 0, stream>>>(qb, kb, vT, y);
  k_lora_u<<<dim3(128, 4), 256, 0, stream>>>(y, dl, u, 3, 1);
  k_gemm<<<gg, 256, 0, stream>>>(y, Wb[3], u, dl, (void*)d_out, 3, 2);
}

// Round 3
// 380.792 us; speedup vs baseline: 1.5303x; 1.5303x over previous
//
#include <hip/hip_runtime.h>
#include <cstdint>
#include <cstddef>

// ---------- types ----------
typedef __attribute__((ext_vector_type(8))) __bf16 bf8_t;   // MFMA A/B frag (4 VGPR)
typedef __attribute__((ext_vector_type(8))) short s8_t;     // 16B raw copy
typedef __attribute__((ext_vector_type(4))) short s4_t;     // 8B raw
typedef __attribute__((ext_vector_type(4))) float f4_t;     // MFMA C/D frag

__device__ __forceinline__ float bf2f(unsigned short h) {
  union { unsigned u; float f; } v; v.u = (unsigned)h << 16; return v.f;
}
__device__ __forceinline__ unsigned short f2bf(float f) {
  union { float f; unsigned u; } v; v.f = f;
  return (unsigned short)((v.u + 0x7FFFu + ((v.u >> 16) & 1u)) >> 16);
}

#define GL16(gp, lp) __builtin_amdgcn_global_load_lds( \
    (__attribute__((address_space(1))) void*)(gp),     \
    (__attribute__((address_space(3))) void*)(lp), 16, 0, 0)

// ---------- fp32 -> bf16 conversion ----------
__global__ void k_f32_to_bf16(const float* __restrict__ in,
                              unsigned short* __restrict__ out, int n4) {
  int i = blockIdx.x * blockDim.x + threadIdx.x;
  if (i >= n4) return;
  float4 v = reinterpret_cast<const float4*>(in)[i];
  s4_t o;
  o.x = (short)f2bf(v.x); o.y = (short)f2bf(v.y);
  o.z = (short)f2bf(v.z); o.w = (short)f2bf(v.w);
  reinterpret_cast<s4_t*>(out)[i] = o;
}

// ---------- RoPE cos/sin table (T=1024, 64 freqs) ----------
__global__ void k_rope_table(float* __restrict__ cosT, float* __restrict__ sinT) {
  int t = blockIdx.x, d = threadIdx.x;            // 1024 x 64
  float inv = exp2f(-(float)d * (13.287712379549449f / 64.0f)); // 10000^(-d/64)
  float ang = (float)t * inv;
  cosT[t * 64 + d] = cosf(ang);
  sinT[t * 64 + d] = sinf(ang);
}

// ---------- LoRA u = X @ dA^T via MFMA (u: [B][4][16][1024] f32) ----------
// grid (16, B); 256 threads = 4 waves; M-tile 64 (16/wave), N = pcount*16, K=2048
__global__ __launch_bounds__(256) void k_lora_mfma(
    const unsigned short* __restrict__ X,    // (B,1024,2048) bf16
    const unsigned short* __restrict__ dlb,  // (B,128,2048) bf16
    float* __restrict__ u, int pstart, int pcount) {
  __shared__ __align__(16) unsigned short Xs[64 * 64];
  __shared__ __align__(16) unsigned short Da[64 * 64];
  const int t = threadIdx.x;
  const int b = blockIdx.y;
  const int m0 = blockIdx.x * 64;
  const int w = t >> 6, lane = t & 63, lr = lane & 15, lg = lane >> 4;
  const int nrow = pcount * 16;
  f4_t acc[4] = {};
  for (int k0 = 0; k0 < 2048; k0 += 64) {
    __syncthreads();
#pragma unroll
    for (int i = 0; i < 2; ++i) {
      int idx = i * 256 + t;
      int row = idx >> 3, c = idx & 7;
      GL16(X + ((size_t)b * 1024 + m0 + row) * 2048 + k0 + ((c ^ (row & 7)) * 8),
           Xs + (size_t)idx * 8);
      int ric = row < nrow ? row : nrow - 1;
      int g = (pstart + (ric >> 4)) * 32 + (ric & 15);
      GL16(dlb + ((size_t)b * 128 + g) * 2048 + k0 + ((c ^ (ric & 7)) * 8),
           Da + (size_t)idx * 8);
    }
    __syncthreads();
#pragma unroll
    for (int kk = 0; kk < 2; ++kk) {
      bf8_t af = *(const bf8_t*)&Xs[(w * 16 + lr) * 64 + (((kk * 4 + lg) ^ (lr & 7)) * 8)];
#pragma unroll
      for (int n = 0; n < 4; ++n) {
        if (n < pcount) {
          bf8_t bfv = *(const bf8_t*)&Da[(n * 16 + lr) * 64 + (((kk * 4 + lg) ^ (lr & 7)) * 8)];
          acc[n] = __builtin_amdgcn_mfma_f32_16x16x32_bf16(af, bfv, acc[n], 0, 0, 0);
        }
      }
    }
  }
#pragma unroll
  for (int n = 0; n < 4; ++n) {
    if (n < pcount) {
#pragma unroll
      for (int j = 0; j < 4; ++j)
        u[(((size_t)b * 4 + pstart + n) * 16 + lr) * 1024 + m0 + w * 16 + lg * 4 + j] = acc[n][j];
    }
  }
}

// ---------- 128x128 bf16 GEMM (A:MxK, Bw:NxK both K-major) + LoRA epilogue ----------
// mode 0: out (B,H,T,D) bf16   mode 1: out (B,H,D,T) bf16   mode 2: out (B,T,C) f32
struct GArgs {
  const unsigned short *Bw0, *Bw1, *Bw2;
  void *o0, *o1, *o2;
  int m0_, m1_, m2_;   // modes
  int p0_, p1_, p2_;   // LoRA p index
};
#define BM 128
#define BN 128
#define BKK 64
__global__ __launch_bounds__(256, 2) void k_gemm(
    const unsigned short* __restrict__ A,
    GArgs ga,
    const float* __restrict__ u,
    const float* __restrict__ dl) {
  constexpr int K = 2048;
  const int z = blockIdx.z;
  const unsigned short* Bw = z == 0 ? ga.Bw0 : (z == 1 ? ga.Bw1 : ga.Bw2);
  void* outv = z == 0 ? ga.o0 : (z == 1 ? ga.o1 : ga.o2);
  const int mode = z == 0 ? ga.m0_ : (z == 1 ? ga.m1_ : ga.m2_);
  const int p = z == 0 ? ga.p0_ : (z == 1 ? ga.p1_ : ga.p2_);
  __shared__ unsigned short As[BM * BKK];   // 16 KB
  __shared__ unsigned short Bs[BN * BKK];   // 16 KB
  const int t = threadIdx.x;
  const int m0 = blockIdx.y * BM;
  const int n0 = blockIdx.x * BN;
  const int lane = t & 63;
  const int w = t >> 6;
  const int wr = (w >> 1) * 64, wc = (w & 1) * 64;
  const int lr = lane & 15;
  const int lg = lane >> 4;
  const int lk = lg * 8;
  const int srow = t >> 3;          // 0..31
  const int scol = (t & 7) * 8;     // 0..56 (elems)
  f4_t acc[4][4] = {};

  for (int k0 = 0; k0 < K; k0 += BKK) {
#pragma unroll
    for (int j = 0; j < 4; ++j) {
      int row = j * 32 + srow;
      GL16(A  + (size_t)(m0 + row) * K + k0 + scol, As + row * BKK + scol);
      GL16(Bw + (size_t)(n0 + row) * K + k0 + scol, Bs + row * BKK + scol);
    }
    __syncthreads();
#pragma unroll
    for (int kk = 0; kk < BKK; kk += 32) {
      bf8_t af[4], bfr[4];
#pragma unroll
      for (int m = 0; m < 4; ++m)
        af[m] = *(const bf8_t*)&As[(wr + m * 16 + lr) * BKK + kk + lk];
#pragma unroll
      for (int n = 0; n < 4; ++n)
        bfr[n] = *(const bf8_t*)&Bs[(wc + n * 16 + lr) * BKK + kk + lk];
#pragma unroll
      for (int m = 0; m < 4; ++m)
#pragma unroll
        for (int n = 0; n < 4; ++n)
          acc[m][n] = __builtin_amdgcn_mfma_f32_16x16x32_bf16(af[m], bfr[n], acc[m][n], 0, 0, 0);
    }
    __syncthreads();
  }

  // LoRA rank-16 as one zero-padded K=32 MFMA step
  const int b = m0 >> 10;
  const int t0r = m0 & 1023;
  for (int idx = t; idx < 128 * 32; idx += 256) {
    int rr = idx >> 5, r = idx & 31;
    float val = (r < 16) ? u[(((size_t)b * 4 + p) * 16 + r) * 1024 + t0r + rr] : 0.0f;
    As[rr * 32 + r] = f2bf(val);
  }
  for (int idx = t; idx < 128 * 32; idx += 256) {
    int cc = idx >> 5, r = idx & 31;
    float val = (r < 16) ? dl[((size_t)b * 128 + p * 32 + 16 + r) * 2048 + n0 + cc] : 0.0f;
    Bs[cc * 32 + r] = f2bf(val);
  }
  __syncthreads();
  {
    bf8_t af[4], bfr[4];
#pragma unroll
    for (int m = 0; m < 4; ++m)
      af[m] = *(const bf8_t*)&As[(wr + m * 16 + lr) * 32 + lk];
#pragma unroll
    for (int n = 0; n < 4; ++n)
      bfr[n] = *(const bf8_t*)&Bs[(wc + n * 16 + lr) * 32 + lk];
#pragma unroll
    for (int m = 0; m < 4; ++m)
#pragma unroll
      for (int n = 0; n < 4; ++n)
        acc[m][n] = __builtin_amdgcn_mfma_f32_16x16x32_bf16(af[m], bfr[n], acc[m][n], 0, 0, 0);
  }

  // write (C/D map: col = lane&15, row = (lane>>4)*4 + reg)
  unsigned short* out16 = (unsigned short*)outv;
  float* out32 = (float*)outv;
#pragma unroll
  for (int m = 0; m < 4; ++m) {
    int ri = wr + m * 16 + lg * 4;
#pragma unroll
    for (int j = 0; j < 4; ++j) {
      int grow = m0 + ri + j;
      int gb = grow >> 10, gt = grow & 1023;
#pragma unroll
      for (int n = 0; n < 4; ++n) {
        int gcol = n0 + wc + n * 16 + lr;
        float fv = acc[m][n][j];
        if (mode == 0) {
          size_t dst = (((size_t)gb * 16 + (gcol >> 7)) * 1024 + gt) * 128 + (gcol & 127);
          out16[dst] = f2bf(fv);
        } else if (mode == 1) {
          size_t dst = (((size_t)gb * 16 + (gcol >> 7)) * 128 + (gcol & 127)) * 1024 + gt;
          out16[dst] = f2bf(fv);
        } else {
          out32[(size_t)grow * 2048 + gcol] = fv;   // final output is FLOAT32
        }
      }
    }
  }
}

// ---------- in-place RoPE on (B,H,T,128) bf16 ----------
__global__ void k_rope(unsigned short* __restrict__ X,
                       const float* __restrict__ cosT, const float* __restrict__ sinT) {
  int idx = blockIdx.x * 256 + threadIdx.x;     // B*H*T*8 = 524288
  int d0 = (idx & 7) * 8;
  int tt = (idx >> 3) & 1023;
  size_t base = (size_t)(idx >> 3) * 128 + d0;  // (bh*1024+t)*128 + d0
  s8_t a = *(s8_t*)&X[base];
  s8_t bb = *(s8_t*)&X[base + 64];
  float4 c0 = *(const float4*)&cosT[tt * 64 + d0];
  float4 c1 = *(const float4*)&cosT[tt * 64 + d0 + 4];
  float4 sv0 = *(const float4*)&sinT[tt * 64 + d0];
  float4 sv1 = *(const float4*)&sinT[tt * 64 + d0 + 4];
  float cv[8] = {c0.x, c0.y, c0.z, c0.w, c1.x, c1.y, c1.z, c1.w};
  float sw[8] = {sv0.x, sv0.y, sv0.z, sv0.w, sv1.x, sv1.y, sv1.z, sv1.w};
  s8_t ra, rb;
#pragma unroll
  for (int j = 0; j < 8; ++j) {
    float av = bf2f((unsigned short)a[j]);
    float bv = bf2f((unsigned short)bb[j]);
    ra[j] = (short)f2bf(av * cv[j] - bv * sw[j]);
    rb[j] = (short)f2bf(bv * cv[j] + av * sw[j]);
  }
  *(s8_t*)&X[base] = ra;
  *(s8_t*)&X[base + 64] = rb;
}

// ---------- fused attention: LDS-staged K/V, 8 waves, online softmax ----------
// Q,K: (B,H,T,128) bf16  Vt: (B,H,D,T) bf16  Y: (B,T,2048) bf16
// grid 512 = bh(64) x qchunk(8), XCD-chunked so one bh stays on one XCD's L2.
__global__ __launch_bounds__(512, 4) void k_attn(
    const unsigned short* __restrict__ Qg,
    const unsigned short* __restrict__ Kg,
    const unsigned short* __restrict__ Vt,
    unsigned short* __restrict__ Y) {
  const float scale = 0.08838834764831845f;  // 1/sqrt(128)
  const float L2E = 1.4426950408889634f;
  const int bid = blockIdx.x;
  const int wg = (bid & 7) * 64 + (bid >> 3);   // bijective, 8 XCD chunks of 64
  const int bh = wg >> 3;
  const int b = bh >> 4, h = bh & 15;
  const int t = threadIdx.x;
  const int w = t >> 6, lane = t & 63;
  const int lr = lane & 15, lg = lane >> 4;
  const int q0 = (wg & 7) * 128 + w * 16;
  const unsigned short* Q  = Qg + (size_t)bh * 131072;
  const unsigned short* Kp = Kg + (size_t)bh * 131072;
  const unsigned short* Vp = Vt + (size_t)bh * 131072;
  __shared__ __align__(16) unsigned short Ks[64 * 128];    // [s][dchunk^swz] 16KB
  __shared__ __align__(16) unsigned short Vs[128 * 64];    // [d][schunk^swz] 16KB
  __shared__ __align__(16) unsigned short Ps[8][16 * 80];  // per-wave P, 20KB
  unsigned short* Pw = Ps[w];

  bf8_t qf[4];
#pragma unroll
  for (int kk = 0; kk < 4; ++kk)
    qf[kk] = *(const bf8_t*)&Q[(size_t)(q0 + lr) * 128 + kk * 32 + lg * 8];

  f4_t o[8] = {};
  float m_run = -1e30f, l_run = 0.0f;

  for (int s0 = 0; s0 < 1024; s0 += 64) {
    __syncthreads();   // all waves done reading previous K/V tile
#pragma unroll
    for (int i = 0; i < 2; ++i) {          // K tile: [64 s][128 d]
      int idx = i * 512 + t;
      int s = idx >> 4, c = t & 15;
      GL16(Kp + (size_t)(s0 + s) * 128 + ((c ^ (s & 7)) * 8), Ks + (size_t)idx * 8);
    }
#pragma unroll
    for (int i = 0; i < 2; ++i) {          // V tile: [128 d][64 s]
      int idx = i * 512 + t;
      int d = idx >> 3, c = t & 7;
      GL16(Vp + (size_t)d * 1024 + s0 + ((c ^ (d & 7)) * 8), Vs + (size_t)idx * 8);
    }
    __syncthreads();   // vmcnt(0) drained by compiler before barrier

    // QK^T (swapped: A=K rows, B=Q rows -> lane holds S[q=q0+lr][s])
    f4_t sf[4];
#pragma unroll
    for (int ss = 0; ss < 4; ++ss) {
      f4_t c = {0.0f, 0.0f, 0.0f, 0.0f};
#pragma unroll
      for (int kk = 0; kk < 4; ++kk) {
        bf8_t kf = *(const bf8_t*)&Ks[(ss * 16 + lr) * 128 + (((kk * 4 + lg) ^ (lr & 7)) * 8)];
        c = __builtin_amdgcn_mfma_f32_16x16x32_bf16(kf, qf[kk], c, 0, 0, 0);
      }
      sf[ss] = c;   // s = s0 + ss*16 + lg*4 + j, q = q0 + lr
    }
    // online softmax over the 64-s tile
    float vmax = -1e30f;
#pragma unroll
    for (int ss = 0; ss < 4; ++ss)
#pragma unroll
      for (int j = 0; j < 4; ++j) vmax = fmaxf(vmax, sf[ss][j]);
    vmax = fmaxf(vmax, __shfl_xor(vmax, 16));
    vmax = fmaxf(vmax, __shfl_xor(vmax, 32));
    float m_new = fmaxf(m_run, vmax * scale);
    float ratio = exp2f((m_run - m_new) * L2E);
    float lsum = 0.0f;
    float ps[4][4];
#pragma unroll
    for (int ss = 0; ss < 4; ++ss)
#pragma unroll
      for (int j = 0; j < 4; ++j) {
        float pv = exp2f((sf[ss][j] * scale - m_new) * L2E);
        ps[ss][j] = pv; lsum += pv;
      }
    lsum += __shfl_xor(lsum, 16);
    lsum += __shfl_xor(lsum, 32);
    l_run = l_run * ratio + lsum;
    m_run = m_new;
    float rq[4];
#pragma unroll
    for (int j = 0; j < 4; ++j) rq[j] = __shfl(ratio, lg * 4 + j);
#pragma unroll
    for (int n = 0; n < 8; ++n)
#pragma unroll
      for (int j = 0; j < 4; ++j) o[n][j] *= rq[j];
    // P -> per-wave LDS (row q=lr, 64 s cols, stride 80 keeps 16B alignment)
#pragma unroll
    for (int ss = 0; ss < 4; ++ss) {
      s4_t pk;
      pk.x = (short)f2bf(ps[ss][0]); pk.y = (short)f2bf(ps[ss][1]);
      pk.z = (short)f2bf(ps[ss][2]); pk.w = (short)f2bf(ps[ss][3]);
      *(s4_t*)&Pw[lr * 80 + ss * 16 + lg * 4] = pk;
    }
    bf8_t pa0 = *(const bf8_t*)&Pw[lr * 80 + lg * 8];
    bf8_t pa1 = *(const bf8_t*)&Pw[lr * 80 + 32 + lg * 8];
#pragma unroll
    for (int n = 0; n < 8; ++n) {
      int d = n * 16 + lr;
      bf8_t v0 = *(const bf8_t*)&Vs[d * 64 + (((0 + lg) ^ (lr & 7)) * 8)];
      bf8_t v1 = *(const bf8_t*)&Vs[d * 64 + (((4 + lg) ^ (lr & 7)) * 8)];
      o[n] = __builtin_amdgcn_mfma_f32_16x16x32_bf16(pa0, v0, o[n], 0, 0, 0);
      o[n] = __builtin_amdgcn_mfma_f32_16x16x32_bf16(pa1, v1, o[n], 0, 0, 0);
    }
  }

  float linv[4];
#pragma unroll
  for (int j = 0; j < 4; ++j) linv[j] = 1.0f / __shfl(l_run, lg * 4 + j);
#pragma unroll
  for (int n = 0; n < 8; ++n)
#pragma unroll
    for (int j = 0; j < 4; ++j) {
      int qg = q0 + lg * 4 + j;
      Y[((size_t)b * 1024 + qg) * 2048 + h * 128 + n * 16 + lr] =
          f2bf(o[n][j] * linv[j]);
    }
}

// ---------- launch ----------
extern "C" void kernel_launch(void* const* d_in, const int* in_sizes, int n_in,
                              void* d_out, int out_size, void* d_ws, size_t ws_size,
                              hipStream_t stream) {
  const float* x  = (const float*)d_in[0];
  const float* dl = (const float*)d_in[1];
  const float* W[4] = {(const float*)d_in[2], (const float*)d_in[3],
                       (const float*)d_in[4], (const float*)d_in[5]};
  char* ws = (char*)d_ws;
  size_t off = 0;
  auto take = [&](size_t bytes) {
    void* p = ws + off; off += (bytes + 255) & ~(size_t)255; return p;
  };
  unsigned short* xb = (unsigned short*)take(8388608ull * 2);
  unsigned short* Wb[4];
  for (int i = 0; i < 4; ++i) Wb[i] = (unsigned short*)take(4194304ull * 2);
  unsigned short* qb = (unsigned short*)take(8388608ull * 2);
  unsigned short* kb = (unsigned short*)take(8388608ull * 2);
  unsigned short* vT = (unsigned short*)take(8388608ull * 2);
  unsigned short* y  = (unsigned short*)take(8388608ull * 2);
  float* u    = (float*)take(4ull * 4 * 16 * 1024 * 4);
  float* cosT = (float*)take(1024ull * 64 * 4);
  float* sinT = (float*)take(1024ull * 64 * 4);
  unsigned short* dlb = (unsigned short*)take(1048576ull * 2);
  if (off > ws_size) return;  // workspace too small -> visible validation failure

  k_f32_to_bf16<<<8192, 256, 0, stream>>>(x, xb, 2097152);
  for (int i = 0; i < 4; ++i)
    k_f32_to_bf16<<<4096, 256, 0, stream>>>(W[i], Wb[i], 1048576);
  k_f32_to_bf16<<<1024, 256, 0, stream>>>(dl, dlb, 262144);
  k_rope_table<<<1024, 64, 0, stream>>>(cosT, sinT);
  k_lora_mfma<<<dim3(16, 4), 256, 0, stream>>>(xb, dlb, u, 0, 3);

  GArgs gq;
  gq.Bw0 = Wb[0]; gq.o0 = qb;    gq.m0_ = 0; gq.p0_ = 0;
  gq.Bw1 = Wb[1]; gq.o1 = kb;    gq.m1_ = 0; gq.p1_ = 1;
  gq.Bw2 = Wb[2]; gq.o2 = vT;    gq.m2_ = 1; gq.p2_ = 2;
  k_gemm<<<dim3(16, 32, 3), 256, 0, stream>>>(xb, gq, u, dl);

  k_rope<<<2048, 256, 0, stream>>>(qb, cosT, sinT);
  k_rope<<<2048, 256, 0, stream>>>(kb, cosT, sinT);
  k_attn<<<512, 512, 0, stream>>>(qb, kb, vT, y);
  k_lora_mfma<<<dim3(16, 4), 256, 0, stream>>>(y, dlb, u, 3, 1);

  GArgs go;
  go.Bw0 = Wb[3]; go.o0 = d_out; go.m0_ = 2; go.p0_ = 3;
  go.Bw1 = Wb[3]; go.o1 = d_out; go.m1_ = 2; go.p1_ = 3;
  go.Bw2 = Wb[3]; go.o2 = d_out; go.m2_ = 2; go.p2_ = 3;
  k_gemm<<<dim3(16, 32, 1), 256, 0, stream>>>(y, go, u, dl);
}